// Round 1
// 15017.113 us; speedup vs baseline: 1.0077x; 1.0077x over previous
//
#include <hip/hip_runtime.h>
#include <hip/hip_bf16.h>
#include <stdint.h>

// Problem: out[b, q*32+f, n, t] = sum_p s_qp * sum_m A_{q^p}[n,m] * x[b, p*32+f, m, t]
// B=16, C=128 (F=32 per quaternion quarter), N=4096, T=12.
#define Bn   16
#define Cn   128
#define Fq   32
#define Nn   4096
#define Tn   12
#define KK   4096
#define COLS 6144   // Bn*Fq*Tn columns per quarter

typedef __bf16 bf16x8 __attribute__((ext_vector_type(8)));
typedef float  f32x4  __attribute__((ext_vector_type(4)));
typedef uint32_t u32x4 __attribute__((ext_vector_type(4)));

__device__ __forceinline__ uint16_t f2bf(float x) {
  uint32_t u = __float_as_uint(x);
  u = (u + 0x7fffu + ((u >> 16) & 1u)) >> 16;   // round-to-nearest-even
  return (uint16_t)u;
}

// ---------------------------------------------------------------------------
// Pack A: 4 fp32 [4096x4096] matrices -> bf16 Ab[4][4096][4096] (row-major,
// k-contiguous). grid (8192, 4) x 256 threads, 8 elems/thread.
// ---------------------------------------------------------------------------
__global__ void pack_a_kernel(const float* __restrict__ Ar, const float* __restrict__ Ai,
                              const float* __restrict__ Aj, const float* __restrict__ Ak,
                              uint16_t* __restrict__ Ab) {
  const int a = blockIdx.y;
  const float* src = (a == 0) ? Ar : (a == 1) ? Ai : (a == 2) ? Aj : Ak;
  size_t idx = ((size_t)blockIdx.x * 256 + threadIdx.x) * 8;
  const float4* s4 = (const float4*)(src + idx);
  float4 v0 = s4[0], v1 = s4[1];
  u32x4 w;
  w[0] = (uint32_t)f2bf(v0.x) | ((uint32_t)f2bf(v0.y) << 16);
  w[1] = (uint32_t)f2bf(v0.z) | ((uint32_t)f2bf(v0.w) << 16);
  w[2] = (uint32_t)f2bf(v1.x) | ((uint32_t)f2bf(v1.y) << 16);
  w[3] = (uint32_t)f2bf(v1.z) | ((uint32_t)f2bf(v1.w) << 16);
  *(u32x4*)(Ab + (size_t)a * KK * KK + idx) = w;
}

// ---------------------------------------------------------------------------
// Pack X: x fp32 [B,C,N,T] -> bf16 Xp[p][col][m], col=(b*32+f)*12+t, m contig.
// grid (16, 2048=(p*16+b)*32+f) x 256 threads; thread owns one m, 12 t's.
// ---------------------------------------------------------------------------
__global__ void pack_x_kernel(const float* __restrict__ x, uint16_t* __restrict__ Xp) {
  const int y  = blockIdx.y;
  const int f  = y & 31;
  const int pb = y >> 5;
  const int b  = pb & 15;
  const int p  = pb >> 4;
  const int m  = blockIdx.x * 256 + threadIdx.x;
  const float* slab = x + ((size_t)(b * Cn + p * Fq + f) * Nn + m) * Tn;
  float4 v0 = *(const float4*)(slab);
  float4 v1 = *(const float4*)(slab + 4);
  float4 v2 = *(const float4*)(slab + 8);
  float v[12] = {v0.x, v0.y, v0.z, v0.w, v1.x, v1.y, v1.z, v1.w, v2.x, v2.y, v2.z, v2.w};
  size_t colBase = (size_t)p * COLS + (size_t)(b * Fq + f) * Tn;
  uint16_t* op = Xp + colBase * KK + m;
#pragma unroll
  for (int t = 0; t < 12; t++) op[(size_t)t * KK] = f2bf(v[t]);
}

// ---------------------------------------------------------------------------
// Fused quaternion GEMM. Block = 256 thr = 4 waves; block tile 64 n x 64 col.
// Wave q owns output quarter q: acc[4][4] accumulating sum_p s_qp * A_{q^p} x_p.
// This round:
//  (1) LDS XOR-swizzle (T2, rule #21 both-sides): global SOURCE chunk is
//      pre-swizzled (skc = skb ^ ((srow>>1)&3)); global_load_lds dest stays
//      linear; fragment reads apply the same XOR. Kills the 8-way bank
//      conflict of the 64-B-row layout (slot = (4r+akb)&7 hit 2 slots/16 rows).
//  (2) Double-buffered LDS + prefetch: issue next K-tile's global_load_lds
//      BEFORE computing the current tile; single __syncthreads per iter whose
//      implicit vmcnt(0) drain lands after compute -> stage/compute overlap.
// ---------------------------------------------------------------------------
__global__ __launch_bounds__(256) void qgemm_kernel(const uint16_t* __restrict__ Ab,
                                                    const uint16_t* __restrict__ Xp,
                                                    float* __restrict__ out) {
  __shared__ uint16_t As[2][4 * 64 * 32];  // [buf][a][row][k]  32 KB x2
  __shared__ uint16_t Xs[2][4 * 64 * 32];  // [buf][p][col][k]  32 KB x2

  const int tid  = threadIdx.x;
  const int lane = tid & 63;
  const int q    = tid >> 6;            // output quarter handled by this wave

  // Block swizzle: 1024-block groups = all 64 n-tiles x 16 col-tiles.
  const int gid   = blockIdx.x;
  const int group = gid >> 10;
  const int wi    = gid & 1023;
  const int nT    = wi & 63;
  const int cT    = (group << 4) | (wi >> 6);
  const int n0    = nT * 64;
  const int c0    = cT * 64;

  f32x4 acc[4][4];
#pragma unroll
  for (int i = 0; i < 4; i++)
#pragma unroll
    for (int j = 0; j < 4; j++) acc[i][j] = (f32x4){0.f, 0.f, 0.f, 0.f};

  const int srow = tid >> 2;                  // staging row/col within tile
  const int skb  = tid & 3;                   // staging 16B chunk (LDS dest)
  const int skc  = skb ^ ((srow >> 1) & 3);   // pre-swizzled SOURCE chunk

  // negate mask per quarter: which A-matrix fragments get their sign flipped
  const int negm = (q == 0) ? 0xE : (q == 1) ? 0x8 : (q == 2) ? 0x2 : 0x4;

  const int arow = lane & 15;   // MFMA A/B frag row/col
  const int akb  = lane >> 4;   // k-chunk (8 consecutive k per lane)
  const int koff = (akb ^ ((arow >> 1) & 3)) * 8;  // swizzled read chunk offset

  // loop-invariant per-thread staging offsets (k0 added per iter)
  const size_t aOff = (size_t)(n0 + srow) * KK + skc * 8;
  const size_t xOff = (size_t)(c0 + srow) * KK + skc * 8;

#define STAGE(buf, k0)                                                                          \
  do {                                                                                          \
    _Pragma("unroll")                                                                           \
    for (int a = 0; a < 4; a++) {                                                               \
      const uint16_t* g = Ab + (size_t)a * KK * KK + aOff + (k0);                               \
      __builtin_amdgcn_global_load_lds((const __attribute__((address_space(1))) uint32_t*)g,    \
                                       (__attribute__((address_space(3))) uint32_t*)            \
                                           &As[buf][a * 2048 + tid * 8],                        \
                                       16, 0, 0);                                               \
    }                                                                                           \
    _Pragma("unroll")                                                                           \
    for (int p = 0; p < 4; p++) {                                                               \
      const uint16_t* g = Xp + (size_t)p * COLS * KK + xOff + (k0);                             \
      __builtin_amdgcn_global_load_lds((const __attribute__((address_space(1))) uint32_t*)g,    \
                                       (__attribute__((address_space(3))) uint32_t*)            \
                                           &Xs[buf][p * 2048 + tid * 8],                        \
                                       16, 0, 0);                                               \
    }                                                                                           \
  } while (0)

  // Prologue: stage first K-tile into buf 0.
  STAGE(0, 0);
  __syncthreads();  // drains vmcnt(0): buf0 visible

  for (int kt = 0; kt < 128; kt++) {
    const int cur = kt & 1;
    if (kt < 127) STAGE(cur ^ 1, (kt + 1) * 32);  // prefetch next tile (uniform branch)

    // ---- compute current tile from LDS (swizzled reads) ----
    bf16x8 af[4][4];
#pragma unroll
    for (int a = 0; a < 4; a++) {
#pragma unroll
      for (int mt = 0; mt < 4; mt++) {
        bf16x8 v = *(const bf16x8*)&As[cur][a * 2048 + (mt * 16 + arow) * 32 + koff];
        if (negm & (1 << a)) {  // wave-uniform branch
          u32x4 u = __builtin_bit_cast(u32x4, v);
          u ^= 0x80008000u;
          v = __builtin_bit_cast(bf16x8, u);
        }
        af[a][mt] = v;
      }
    }
#pragma unroll
    for (int p = 0; p < 4; p++) {
      const int a = q ^ p;  // Hamilton-product A index for (quarter q, x-part p)
#pragma unroll
      for (int nt = 0; nt < 4; nt++) {
        bf16x8 bfr = *(const bf16x8*)&Xs[cur][p * 2048 + (nt * 16 + arow) * 32 + koff];
#pragma unroll
        for (int mt = 0; mt < 4; mt++) {
          acc[mt][nt] = __builtin_amdgcn_mfma_f32_16x16x32_bf16(af[a][mt], bfr, acc[mt][nt], 0, 0, 0);
        }
      }
    }

    // Single barrier per iter: implicit s_waitcnt vmcnt(0) lgkmcnt(0) drains the
    // prefetch (issued ~full compute phase ago) and protects buf[cur] reuse.
    __syncthreads();
  }
#undef STAGE

  // Epilogue: C/D layout col=lane&15, row=(lane>>4)*4+reg (m89-verified).
#pragma unroll
  for (int nt = 0; nt < 4; nt++) {
    int colIdx = c0 + nt * 16 + (lane & 15);
    int b   = colIdx / 384;          // 384 = Fq*Tn
    int rem = colIdx - b * 384;
    int f   = rem / 12;
    int t   = rem - f * 12;
    size_t chanBase = (size_t)(b * Cn + q * Fq + f) * Nn * Tn + t;
#pragma unroll
    for (int mt = 0; mt < 4; mt++) {
      int n = n0 + mt * 16 + (lane >> 4) * 4;
      float* o = out + chanBase + (size_t)n * Tn;
      f32x4 v = acc[mt][nt];
      o[0] = v[0]; o[12] = v[1]; o[24] = v[2]; o[36] = v[3];
    }
  }
}

// ---------------------------------------------------------------------------
extern "C" void kernel_launch(void* const* d_in, const int* in_sizes, int n_in,
                              void* d_out, int out_size, void* d_ws, size_t ws_size,
                              hipStream_t stream) {
  const float* x  = (const float*)d_in[0];
  const float* Ar = (const float*)d_in[1];
  const float* Ai = (const float*)d_in[2];
  const float* Aj = (const float*)d_in[3];
  const float* Ak = (const float*)d_in[4];
  float* out = (float*)d_out;

  // ws layout: Ab bf16 [4][4096][4096] = 134,217,728 B; Xp bf16 [4][6144][4096]
  // = 201,326,592 B; total 335,544,320 B required of ws_size.
  uint16_t* Ab = (uint16_t*)d_ws;
  uint16_t* Xp = (uint16_t*)((char*)d_ws + (size_t)4 * KK * KK * 2);

  pack_a_kernel<<<dim3(8192, 4), 256, 0, stream>>>(Ar, Ai, Aj, Ak, Ab);
  pack_x_kernel<<<dim3(16, 2048), 256, 0, stream>>>(x, Xp);
  qgemm_kernel<<<dim3(6144), 256, 0, stream>>>(Ab, Xp, out);
}

// Round 3
// 4342.125 us; speedup vs baseline: 3.4851x; 3.4585x over previous
//
#include <hip/hip_runtime.h>
#include <hip/hip_bf16.h>
#include <stdint.h>

// Problem: out[b, q*32+f, n, t] = sum_p s_qp * sum_m A_{q^p}[n,m] * x[b, p*32+f, m, t]
// B=16, C=128 (F=32 per quaternion quarter), N=4096, T=12.
#define Bn   16
#define Cn   128
#define Fq   32
#define Nn   4096
#define Tn   12
#define KK   4096
#define COLS 6144   // Bn*Fq*Tn columns per quarter

typedef __bf16 bf16x8 __attribute__((ext_vector_type(8)));
typedef float  f32x4  __attribute__((ext_vector_type(4)));
typedef uint32_t u32x4 __attribute__((ext_vector_type(4)));

__device__ __forceinline__ uint16_t f2bf(float x) {
  uint32_t u = __float_as_uint(x);
  u = (u + 0x7fffu + ((u >> 16) & 1u)) >> 16;   // round-to-nearest-even
  return (uint16_t)u;
}

// ---------------------------------------------------------------------------
// Pack A: 4 fp32 [4096x4096] matrices -> bf16 Ab[4][4096][4096] (row-major,
// k-contiguous). grid (8192, 4) x 256 threads, 8 elems/thread.
// ---------------------------------------------------------------------------
__global__ void pack_a_kernel(const float* __restrict__ Ar, const float* __restrict__ Ai,
                              const float* __restrict__ Aj, const float* __restrict__ Ak,
                              uint16_t* __restrict__ Ab) {
  const int a = blockIdx.y;
  const float* src = (a == 0) ? Ar : (a == 1) ? Ai : (a == 2) ? Aj : Ak;
  size_t idx = ((size_t)blockIdx.x * 256 + threadIdx.x) * 8;
  const float4* s4 = (const float4*)(src + idx);
  float4 v0 = s4[0], v1 = s4[1];
  u32x4 w;
  w[0] = (uint32_t)f2bf(v0.x) | ((uint32_t)f2bf(v0.y) << 16);
  w[1] = (uint32_t)f2bf(v0.z) | ((uint32_t)f2bf(v0.w) << 16);
  w[2] = (uint32_t)f2bf(v1.x) | ((uint32_t)f2bf(v1.y) << 16);
  w[3] = (uint32_t)f2bf(v1.z) | ((uint32_t)f2bf(v1.w) << 16);
  *(u32x4*)(Ab + (size_t)a * KK * KK + idx) = w;
}

// ---------------------------------------------------------------------------
// Pack X: x fp32 [B,C,N,T] -> bf16 Xp[p][col][m], col=(b*32+f)*12+t, m contig.
// grid (16, 2048=(p*16+b)*32+f) x 256 threads; thread owns one m, 12 t's.
// ---------------------------------------------------------------------------
__global__ void pack_x_kernel(const float* __restrict__ x, uint16_t* __restrict__ Xp) {
  const int y  = blockIdx.y;
  const int f  = y & 31;
  const int pb = y >> 5;
  const int b  = pb & 15;
  const int p  = pb >> 4;
  const int m  = blockIdx.x * 256 + threadIdx.x;
  const float* slab = x + ((size_t)(b * Cn + p * Fq + f) * Nn + m) * Tn;
  float4 v0 = *(const float4*)(slab);
  float4 v1 = *(const float4*)(slab + 4);
  float4 v2 = *(const float4*)(slab + 8);
  float v[12] = {v0.x, v0.y, v0.z, v0.w, v1.x, v1.y, v1.z, v1.w, v2.x, v2.y, v2.z, v2.w};
  size_t colBase = (size_t)p * COLS + (size_t)(b * Fq + f) * Tn;
  uint16_t* op = Xp + colBase * KK + m;
#pragma unroll
  for (int t = 0; t < 12; t++) op[(size_t)t * KK] = f2bf(v[t]);
}

// ---------------------------------------------------------------------------
// Fused quaternion GEMM, round 3 (= round 2 structure + race hardening):
//  - Block = 512 thr = 8 waves. Tile 128 n x 128 col, BK=32. Wave (q, h):
//    quarter q, row-half h; acc[4][8] f32x4 (64 rows x 128 cols).
//  - LDS: As[2][4][128][32] + Xs[2][4][128][32] = 128 KB, double-buffered.
//    1 block/CU. Staged traffic halves vs 64x64 tile: 12.9 GB total.
//  - Counted-vmcnt pipeline (T4): per iter issue next tile's 8 global_load_lds
//    THEN s_waitcnt vmcnt(8) (current tile landed; next stays in flight)
//    -> raw s_barrier -> compute -> s_barrier. Never vmcnt(0) in main loop.
//  - HARDENING: sched_barrier(0) after the end-of-iter s_barrier. LLVM's
//    s_barrier intrinsic is not a memory-motion fence; without the pin the
//    next iteration's global_load_lds (which overwrite buf[cur]) could be
//    hoisted above the barrier while other waves still read buf[cur].
//  - XCD-chunked bijective swizzle (T1), n-tile fast: each XCD's 32 resident
//    blocks = all 32 n-tiles of one col-tile -> X panel (4 MB) fits XCD L2;
//    A k-slice identical across XCDs -> L3-served (A=134 MB stays hot).
//  - LDS XOR swizzle retained (round-1-verified: 0 bank conflicts).
// ---------------------------------------------------------------------------
__global__ __launch_bounds__(512, 2) void qgemm_kernel(const uint16_t* __restrict__ Ab,
                                                       const uint16_t* __restrict__ Xp,
                                                       float* __restrict__ out) {
  __shared__ uint16_t As[2][4 * 128 * 32];  // [buf][a][row][k]  32 KB/buf
  __shared__ uint16_t Xs[2][4 * 128 * 32];  // [buf][p][col][k]  32 KB/buf

  const int tid  = threadIdx.x;
  const int lane = tid & 63;
  const int wid  = tid >> 6;   // 0..7
  const int q    = wid & 3;    // output quarter
  const int h    = wid >> 2;   // row half (0..1)

  // XCD-chunked bijective swizzle: 1536 blocks = 8 XCDs x 192 (exact).
  const int gid = blockIdx.x;
  const int lid = (gid & 7) * 192 + (gid >> 3);
  const int nT  = lid & 31;
  const int cT  = lid >> 5;
  const int n0  = nT * 128;
  const int c0  = cT * 128;

  f32x4 acc[4][8];
#pragma unroll
  for (int i = 0; i < 4; i++)
#pragma unroll
    for (int j = 0; j < 8; j++) acc[i][j] = (f32x4){0.f, 0.f, 0.f, 0.f};

  const int srow = tid >> 2;                  // staging row/col 0..127
  const int skb  = tid & 3;                   // staging 16B chunk (LDS dest, linear)
  const int skc  = skb ^ ((srow >> 1) & 3);   // pre-swizzled SOURCE chunk

  // negate mask per quarter: which A-matrix fragments get sign-flipped
  const int negm = (q == 0) ? 0xE : (q == 1) ? 0x8 : (q == 2) ? 0x2 : 0x4;

  const int arow = lane & 15;   // MFMA frag row/col
  const int akb  = lane >> 4;   // k-chunk (8 consecutive k per lane)
  const int koff = (akb ^ ((arow >> 1) & 3)) * 8;  // swizzled read chunk (u16 units)

  const size_t aOff = (size_t)(n0 + srow) * KK + skc * 8;
  const size_t xOff = (size_t)(c0 + srow) * KK + skc * 8;

  // 8 global_load_lds per thread per K-step; dest linear (tid*16B per operand
  // slab), source pre-swizzled (rule #21 both-sides).
#define STAGE(buf, k0)                                                                          \
  do {                                                                                          \
    _Pragma("unroll")                                                                           \
    for (int a = 0; a < 4; a++) {                                                               \
      const uint16_t* g = Ab + (size_t)a * KK * KK + aOff + (k0);                               \
      __builtin_amdgcn_global_load_lds((const __attribute__((address_space(1))) uint32_t*)g,    \
                                       (__attribute__((address_space(3))) uint32_t*)            \
                                           &As[buf][a * 4096 + tid * 8],                        \
                                       16, 0, 0);                                               \
    }                                                                                           \
    _Pragma("unroll")                                                                           \
    for (int p = 0; p < 4; p++) {                                                               \
      const uint16_t* g = Xp + (size_t)p * COLS * KK + xOff + (k0);                             \
      __builtin_amdgcn_global_load_lds((const __attribute__((address_space(1))) uint32_t*)g,    \
                                       (__attribute__((address_space(3))) uint32_t*)            \
                                           &Xs[buf][p * 4096 + tid * 8],                        \
                                       16, 0, 0);                                               \
    }                                                                                           \
  } while (0)

  STAGE(0, 0);  // prologue: tile 0 -> buf 0 (8 loads in flight)

  for (int kt = 0; kt < 128; kt++) {
    const int cur = kt & 1;
    if (kt < 127) {
      STAGE(cur ^ 1, (kt + 1) * 32);                    // issue next tile FIRST
      asm volatile("s_waitcnt vmcnt(8)" ::: "memory");  // wait current tile only
    } else {
      asm volatile("s_waitcnt vmcnt(0)" ::: "memory");  // last tile: full drain
    }
    __builtin_amdgcn_s_barrier();        // all waves' staging of buf[cur] landed
    __builtin_amdgcn_sched_barrier(0);   // pin: no ds_read hoisted above barrier

    // ---- compute tile kt from buf[cur] ----
#pragma unroll
    for (int p = 0; p < 4; p++) {
      const int a = q ^ p;  // Hamilton-product A index
      bf16x8 af[4];
#pragma unroll
      for (int mt = 0; mt < 4; mt++) {
        const int row = h * 64 + mt * 16 + arow;
        bf16x8 v = *(const bf16x8*)&As[cur][a * 4096 + row * 32 + koff];
        if (negm & (1 << a)) {  // wave-uniform branch
          u32x4 u = __builtin_bit_cast(u32x4, v);
          u ^= 0x80008000u;
          v = __builtin_bit_cast(bf16x8, u);
        }
        af[mt] = v;
      }
      __builtin_amdgcn_s_setprio(1);
#pragma unroll
      for (int nt = 0; nt < 8; nt++) {
        bf16x8 bfr = *(const bf16x8*)&Xs[cur][p * 4096 + (nt * 16 + arow) * 32 + koff];
#pragma unroll
        for (int mt = 0; mt < 4; mt++) {
          acc[mt][nt] = __builtin_amdgcn_mfma_f32_16x16x32_bf16(af[mt], bfr, acc[mt][nt], 0, 0, 0);
        }
      }
      __builtin_amdgcn_s_setprio(0);
    }

    __builtin_amdgcn_s_barrier();        // compute done before buf[cur] reuse
    __builtin_amdgcn_sched_barrier(0);   // HARDENING: next STAGE stays below
  }
#undef STAGE

  // Epilogue: C/D layout col=lane&15, row=(lane>>4)*4+reg (m89-verified).
#pragma unroll
  for (int nt = 0; nt < 8; nt++) {
    int colIdx = c0 + nt * 16 + (lane & 15);
    int b   = colIdx / 384;          // 384 = Fq*Tn
    int rem = colIdx - b * 384;
    int f   = rem / 12;
    int t   = rem - f * 12;
    size_t chanBase = (size_t)(b * Cn + q * Fq + f) * Nn * Tn + t;
#pragma unroll
    for (int mt = 0; mt < 4; mt++) {
      int n = n0 + h * 64 + mt * 16 + (lane >> 4) * 4;
      float* o = out + chanBase + (size_t)n * Tn;
      f32x4 v = acc[mt][nt];
      o[0] = v[0]; o[12] = v[1]; o[24] = v[2]; o[36] = v[3];
    }
  }
}

// ---------------------------------------------------------------------------
extern "C" void kernel_launch(void* const* d_in, const int* in_sizes, int n_in,
                              void* d_out, int out_size, void* d_ws, size_t ws_size,
                              hipStream_t stream) {
  const float* x  = (const float*)d_in[0];
  const float* Ar = (const float*)d_in[1];
  const float* Ai = (const float*)d_in[2];
  const float* Aj = (const float*)d_in[3];
  const float* Ak = (const float*)d_in[4];
  float* out = (float*)d_out;

  // ws layout: Ab bf16 [4][4096][4096] = 134,217,728 B; Xp bf16 [4][6144][4096]
  // = 201,326,592 B; total 335,544,320 B required of ws_size.
  uint16_t* Ab = (uint16_t*)d_ws;
  uint16_t* Xp = (uint16_t*)((char*)d_ws + (size_t)4 * KK * KK * 2);

  pack_a_kernel<<<dim3(8192, 4), 256, 0, stream>>>(Ar, Ai, Aj, Ak, Ab);
  pack_x_kernel<<<dim3(16, 2048), 256, 0, stream>>>(x, Xp);
  qgemm_kernel<<<dim3(1536), 512, 0, stream>>>(Ab, Xp, out);
}